// Round 3
// baseline (119.398 us; speedup 1.0000x reference)
//
#include <hip/hip_runtime.h>

// TreeModel fused kernel, v6 (resubmit — previous round was an infra failure).
// Tree: complete binary heap, 15 levels (0..14), nodes 0..32766, leaves = nodes 16383..32766.
// out[0..16383] = dot(x[leaf], sum of deltas rows on root->leaf path)
// out[16384]    = sq[0] + sum_{n>=1} sq[n] / max(heights[n]-heights[parent(n)], 1e-7)
//
// v6 changes vs v5: LPB 8 -> 16 (1024 blocks, 4 leaves/wave). Bigger contiguous
// per-block streams (x, lvl14 chunks are 32 KiB), half the concurrent blocks
// (DRAM page locality), half the stage-1 redundant cache traffic (11 shared rows
// amortized over 16 leaves), fewer shuffle-reduce chains per leaf. Ownership:
// each wave uniquely owns its n12 (4095+4b+w), its n13 pair, its 4 leaves;
// waves 0/2 own their n11; wave0 owns upper node b (b<1023); wave1 owns level-10
// node 1023+b. Exactly-once over all 32767 nodes.

constexpr int   N_LEAVES = 16384;
constexpr int   DIM      = 512;
constexpr float MIN_DIST = 1e-7f;
constexpr int   LPB      = 16;                  // leaves per block
constexpr int   GRID     = N_LEAVES / LPB;      // 1024 = 8 XCDs * 128

typedef float v4f __attribute__((ext_vector_type(4)));
typedef float v2f __attribute__((ext_vector_type(2)));

__device__ __forceinline__ float v4dot(v4f a, v4f b) {
    return a.x * b.x + a.y * b.y + a.z * b.z + a.w * b.w;
}
__device__ __forceinline__ float v4sq(v4f a) { return v4dot(a, a); }

__global__ __launch_bounds__(256) void fused_kernel(
        const float* __restrict__ x,
        const float* __restrict__ deltas,
        const float* __restrict__ heights,
        float* __restrict__ out,
        float* __restrict__ partial) {
    __shared__ __align__(16) float wtop[DIM];   // sum of levels 0..10 for this leaf group
    __shared__ float sqred[4];

    const int tid  = threadIdx.x;
    const int lane = tid & 63;
    const int wave = tid >> 6;

    // XCD-contiguous swizzle (bijective: 1024 = 8 * 128).
    const int b = (int)(((blockIdx.x & 7u) << 7) | (blockIdx.x >> 3));

    // ---- Index math (all wave-uniform).
    const int leaf0 = LPB * b + 4 * wave;            // first of this wave's 4 leaves
    const int n14_0 = (N_LEAVES - 1) + leaf0;        // leaves n14_0 .. n14_0+3
    const int n13a  = (n14_0 - 1) >> 1;              // parent of leaves 0,1 = 8191+8b+2w
    const int n13b  = n13a + 1;                      // parent of leaves 2,3
    const int n12   = (n13a - 1) >> 1;               // = 4095+4b+w  (wave-unique)
    const int n11   = (n12 - 1) >> 1;                // = 2047+2b+(w>>1)
    const int n10   = (n11 - 1) >> 1;                // = 1023+b     (block-uniform)

    // ---- (1) Stage-1 loads FIRST (they gate the LDS write + barrier).
    // Thread t accumulates elements [2t, 2t+1] over levels 0..10.
    v2f acc = {0.0f, 0.0f};
    #pragma unroll
    for (int l = 0; l <= 10; ++l) {
        const int node = ((1 << l) - 1) + (b >> (10 - l));
        acc += ((const v2f*)(deltas + (size_t)node * DIM))[tid];
    }

    // ---- (2) sq-extra row loads (upper nodes + level 10), compute deferred.
    v4f ea, ec;
    float escale = 0.0f;
    bool  has_e  = false;
    if (wave == 0 && b < 1023) {                 // levels 0..9: block b owns node b
        const v4f* row = (const v4f*)(deltas + (size_t)b * DIM);
        ea = row[lane]; ec = row[lane + 64];
        escale = (b > 0) ? 1.0f / fmaxf(heights[b] - heights[(b - 1) >> 1], MIN_DIST) : 1.0f;
        has_e = true;
    } else if (wave == 1) {                      // level-10 node 1023+b (1024 nodes exactly)
        const int n = 1023 + b;
        const v4f* row = (const v4f*)(deltas + (size_t)n * DIM);
        ea = row[lane]; ec = row[lane + 64];
        escale = 1.0f / fmaxf(heights[n] - heights[(n - 1) >> 1], MIN_DIST);
        has_e = true;
    }

    // ---- (3) Per-wave delta rows (consumed by sq, pre-barrier).
    const v4f* r11  = (const v4f*)(deltas + (size_t)n11 * DIM);
    const v4f* r12  = (const v4f*)(deltas + (size_t)n12 * DIM);
    const v4f* r13A = (const v4f*)(deltas + (size_t)n13a * DIM);
    const v4f* r13B = (const v4f*)(deltas + (size_t)n13b * DIM);
    v4f a11 = r11[lane],  c11 = r11[lane + 64];
    v4f a12 = r12[lane],  c12 = r12[lane + 64];
    v4f a13A = r13A[lane], c13A = r13A[lane + 64];
    v4f a13B = r13B[lane], c13B = r13B[lane + 64];
    v4f a14[4], c14[4];
    #pragma unroll
    for (int i = 0; i < 4; ++i) {
        const v4f* r = (const v4f*)(deltas + (size_t)(n14_0 + i) * DIM);
        a14[i] = r[lane]; c14[i] = r[lane + 64];
    }

    // ---- (4) x rows LAST (consumed last, after the barrier). 8 KiB contiguous/wave.
    v4f xa[4], xc[4];
    #pragma unroll
    for (int i = 0; i < 4; ++i) {
        const v4f* r = (const v4f*)(x + (size_t)(leaf0 + i) * DIM);
        xa[i] = r[lane]; xc[i] = r[lane + 64];
    }

    // ---- (5) LDS write: waits only on stage-1 loads (earliest issued).
    wtop[2 * tid]     = acc.x;
    wtop[2 * tid + 1] = acc.y;

    // ---- (6) delta_total partials (exactly-once ownership, wave-uniform branches).
    float sq_acc = 0.0f;
    if (has_e) sq_acc += (v4sq(ea) + v4sq(ec)) * escale;
    if ((wave & 1) == 0) {                       // level-11: waves 0,2 own their n11
        sq_acc += (v4sq(a11) + v4sq(c11)) / fmaxf(heights[n11] - heights[n10], MIN_DIST);
    }
    // level-12: wave-unique n12
    sq_acc += (v4sq(a12) + v4sq(c12)) / fmaxf(heights[n12] - heights[n11], MIN_DIST);
    // level-13: both rows of this wave's pair
    sq_acc += (v4sq(a13A) + v4sq(c13A)) / fmaxf(heights[n13a] - heights[n12], MIN_DIST);
    sq_acc += (v4sq(a13B) + v4sq(c13B)) / fmaxf(heights[n13b] - heights[n12], MIN_DIST);
    // level-14: this wave's 4 leaves
    #pragma unroll
    for (int i = 0; i < 4; ++i) {
        const int np = (i < 2) ? n13a : n13b;
        sq_acc += (v4sq(a14[i]) + v4sq(c14[i]))
                / fmaxf(heights[n14_0 + i] - heights[np], MIN_DIST);
    }
    #pragma unroll
    for (int off = 32; off; off >>= 1) sq_acc += __shfl_xor(sq_acc, off, 64);
    if (lane == 0) sqred[wave] = sq_acc;

    __syncthreads();                             // single barrier

    // ---- (7) Block partial -> d_ws (NO atomics); sqred ready at the barrier.
    if (tid == 0) partial[b] = sqred[0] + sqred[1] + sqred[2] + sqred[3];

    // ---- (8) Dot products: w = wtop + n11 + n12 + n13{a,b} + n14_i, dot with x.
    const v4f t0 = ((const v4f*)wtop)[lane];
    const v4f t1 = ((const v4f*)wtop)[lane + 64];
    const v4f base0 = t0 + a11 + a12;
    const v4f base1 = t1 + c11 + c12;
    const v4f bA0 = base0 + a13A, bA1 = base1 + c13A;
    const v4f bB0 = base0 + a13B, bB1 = base1 + c13B;
    float d0 = v4dot(xa[0], bA0 + a14[0]) + v4dot(xc[0], bA1 + c14[0]);
    float d1 = v4dot(xa[1], bA0 + a14[1]) + v4dot(xc[1], bA1 + c14[1]);
    float d2 = v4dot(xa[2], bB0 + a14[2]) + v4dot(xc[2], bB1 + c14[2]);
    float d3 = v4dot(xa[3], bB0 + a14[3]) + v4dot(xc[3], bB1 + c14[3]);
    #pragma unroll
    for (int off = 32; off; off >>= 1) {
        d0 += __shfl_xor(d0, off, 64);
        d1 += __shfl_xor(d1, off, 64);
        d2 += __shfl_xor(d2, off, 64);
        d3 += __shfl_xor(d3, off, 64);
    }
    if (lane == 0) {
        out[leaf0]     = d0;
        out[leaf0 + 1] = d1;
        out[leaf0 + 2] = d2;
        out[leaf0 + 3] = d3;
    }
}

// Single block: reduce 1024 block partials -> out[16384].
__global__ __launch_bounds__(256) void reduce_kernel(
        const float* __restrict__ partial,
        float* __restrict__ out) {
    const int tid = threadIdx.x, lane = tid & 63, wave = tid >> 6;
    const v4f* p = (const v4f*)partial;          // 1024 floats = 256 v4f
    v4f s0 = p[tid];
    float s = s0.x + s0.y + s0.z + s0.w;
    #pragma unroll
    for (int off = 32; off; off >>= 1) s += __shfl_xor(s, off, 64);
    __shared__ float red[4];
    if (lane == 0) red[wave] = s;
    __syncthreads();
    if (tid == 0) out[N_LEAVES] = red[0] + red[1] + red[2] + red[3];
}

extern "C" void kernel_launch(void* const* d_in, const int* in_sizes, int n_in,
                              void* d_out, int out_size, void* d_ws, size_t ws_size,
                              hipStream_t stream) {
    const float* x       = (const float*)d_in[0];
    const float* deltas  = (const float*)d_in[1];
    const float* heights = (const float*)d_in[2];
    float* out     = (float*)d_out;
    float* partial = (float*)d_ws;               // 1024 floats of scratch

    fused_kernel<<<GRID, 256, 0, stream>>>(x, deltas, heights, out, partial);
    reduce_kernel<<<1, 256, 0, stream>>>(partial, out);
}